// Round 7
// baseline (802.961 us; speedup 1.0000x reference)
//
#include <hip/hip_runtime.h>
#include <hip/hip_fp16.h>

#define BATCH 65536
#define DIM   256
#define CODES 1024
#define TAU   0.20f

typedef _Float16 f16x8 __attribute__((ext_vector_type(8)));
typedef float    f32x4 __attribute__((ext_vector_type(4)));

// async global->LDS, 16B per lane; LDS dest = uniform base + lane*16
#define GLL(gptr, lptr) \
    __builtin_amdgcn_global_load_lds( \
        (const __attribute__((address_space(1))) void*)(gptr), \
        (__attribute__((address_space(3))) void*)(lptr), 16, 0, 0)

// ---------------------------------------------------------------------------
// Prep: E -> fp16 + exact |e|^2 per code (f32)
// ---------------------------------------------------------------------------
__global__ void vq_prep(const float* __restrict__ E, float* __restrict__ enorm,
                        unsigned short* __restrict__ Eh) {
    int k = blockIdx.x;      // code
    int lane = threadIdx.x;  // 0..63
    const float4 v = *(const float4*)(E + (size_t)k * DIM + lane * 4);
    float s = v.x * v.x + v.y * v.y + v.z * v.z + v.w * v.w;
    ushort4 hv;
    hv.x = __half_as_ushort(__float2half(v.x));
    hv.y = __half_as_ushort(__float2half(v.y));
    hv.z = __half_as_ushort(__float2half(v.z));
    hv.w = __half_as_ushort(__float2half(v.w));
    *(ushort4*)(Eh + (size_t)k * DIM + lane * 4) = hv;
    s += __shfl_down(s, 32);
    s += __shfl_down(s, 16);
    s += __shfl_down(s, 8);
    s += __shfl_down(s, 4);
    s += __shfl_down(s, 2);
    s += __shfl_down(s, 1);
    if (lane == 0) enorm[k] = s;
}

// ---------------------------------------------------------------------------
// MEGAKERNEL v2: counted-vmcnt pipelined fp16 MFMA argmin + cheap repair +
// fused epilogue.
//   block = 256 thr (4 waves), 64 rows/block, grid = 1024 -> 4 blocks/CU
//   co-resident (LDS ~37 KB), so one block's store phase overlaps another's
//   MFMA phase.
//   Main loop: 4 LDS buffers, prefetch 3 tiles ahead, ONE raw s_barrier +
//   s_waitcnt vmcnt(4) per tile (never 0). STAGE is issued AFTER the
//   barrier: the barrier proves all waves finished reading the buffer being
//   overwritten (WAR), and own-vmcnt-then-barrier proves all waves' tile-t
//   GLLs landed (RAW). Wraparound STAGE index keeps vmcnt(4) literal valid
//   for every iteration.
// ---------------------------------------------------------------------------
__global__ __launch_bounds__(256, 4) void vq_fused(
    const float* __restrict__ X,
    const unsigned short* __restrict__ Eh,
    const float* __restrict__ enorm,
    const float* __restrict__ E,
    float* __restrict__ loss, float* __restrict__ qst, float* __restrict__ onehot) {

    // per buffer: 8 ksteps x 64 lanes x 8 fp16 = 4096 ushort = 8 KB
    __shared__ unsigned short Eb[4][4096];   // 32 KB
    __shared__ float EsL[CODES];             // 4 KB
    __shared__ int   ridx[64];               // per-row chosen index
    __shared__ int   flags[64];              // local rows needing exact repair
    __shared__ int   nflag;
    __shared__ float wrb[4];
    __shared__ int   wri[4];

    const int tid  = threadIdx.x;
    const int lane = tid & 63;
    const int w    = tid >> 6;               // wave 0..3 (stages k-slots w, w+4)
    const int m    = lane & 15;              // A row-in-16 / C code col
    const int quad = lane >> 4;              // 0..3
    const int row0 = blockIdx.x * 64;        // block base row
    const int wrow = row0 + w * 16;          // this wave's first row

    if (tid == 0) nflag = 0;

    // wave w stages slot w (k=w*32) and slot 4+w (k=128+w*32) of tile T
    #define STAGE(T, B) do { \
        const size_t rb_ = (size_t)((T) * 16 + m) * DIM + w * 32 + quad * 8; \
        GLL(Eh + rb_,       &Eb[(B)][w * 512]); \
        GLL(Eh + rb_ + 128, &Eb[(B)][(4 + w) * 512]); \
    } while (0)

    // prologue: stage tiles 0..2 (in flight during A-frag build)
    STAGE(0, 0); STAGE(1, 1); STAGE(2, 2);

    for (int i = tid; i < CODES; i += 256) EsL[i] = enorm[i];

    // ---- A fragments: 16 rows, 8 ksteps fp16 (32 VGPRs) ----
    f16x8 ah[8];
    {
        const float* xr = X + (size_t)(wrow + m) * DIM + quad * 8;
        #pragma unroll
        for (int s = 0; s < 8; ++s) {
            float4 p0 = *(const float4*)(xr + s * 32);
            float4 p1 = *(const float4*)(xr + s * 32 + 4);
            ah[s][0] = (_Float16)p0.x; ah[s][1] = (_Float16)p0.y;
            ah[s][2] = (_Float16)p0.z; ah[s][3] = (_Float16)p0.w;
            ah[s][4] = (_Float16)p1.x; ah[s][5] = (_Float16)p1.y;
            ah[s][6] = (_Float16)p1.z; ah[s][7] = (_Float16)p1.w;
        }
    }

    __syncthreads();   // full drain once: EsL + nflag + prologue tiles 0..2

    float best[4], sec[4];
    int   bidx[4];
    #pragma unroll
    for (int i = 0; i < 4; ++i) { best[i] = 3.4e38f; sec[i] = 3.4e38f; bidx[i] = 0; }

    for (int t = 0; t < 64; ++t) {
        // own tile-t GLLs done (2 newest tiles = 4 ops may stay in flight)...
        asm volatile("s_waitcnt vmcnt(4)" ::: "memory");
        __builtin_amdgcn_sched_barrier(0);
        // ...and everyone else's too; also: all waves done READING buf[(t-1)&3]
        __builtin_amdgcn_s_barrier();
        __builtin_amdgcn_sched_barrier(0);
        // prefetch 3 ahead into the buffer freed by tile t-1 (wraparound
        // index keeps vmcnt uniform; extra tail stages are never read)
        STAGE((t + 3) & 63, (t + 3) & 3);

        f32x4 accA = {0.f, 0.f, 0.f, 0.f}, accB = {0.f, 0.f, 0.f, 0.f};
        const unsigned short* b = &Eb[t & 3][0];
        #pragma unroll
        for (int s = 0; s < 4; ++s) {
            f16x8 bh = *(const f16x8*)(b + s * 512 + lane * 8);
            accA = __builtin_amdgcn_mfma_f32_16x16x32_f16(ah[s], bh, accA, 0, 0, 0);
        }
        #pragma unroll
        for (int s = 4; s < 8; ++s) {
            f16x8 bh = *(const f16x8*)(b + s * 512 + lane * 8);
            accB = __builtin_amdgcn_mfma_f32_16x16x32_f16(ah[s], bh, accB, 0, 0, 0);
        }
        // C layout: col = lane&15 (code), row = quad*4 + reg
        const float es = EsL[t * 16 + m];
        const int   c  = t * 16 + m;
        #pragma unroll
        for (int r = 0; r < 4; ++r) {
            float d = __builtin_fmaf(-2.0f, accA[r] + accB[r], es);
            if (d < best[r]) { sec[r] = best[r]; best[r] = d; bidx[r] = c; }
            else if (d < sec[r]) sec[r] = d;
        }
    }

    // cross-lane argmin reduce over the 16 code-columns (low 4 lane bits)
    #pragma unroll
    for (int i = 0; i < 4; ++i) {
        float b0 = best[i], s0 = sec[i];
        int   i0 = bidx[i];
        #pragma unroll
        for (int msk = 1; msk < 16; msk <<= 1) {
            float ob = __shfl_xor(b0, msk);
            float os = __shfl_xor(s0, msk);
            int   oi = __shfl_xor(i0, msk);
            if (ob < b0 || (ob == b0 && oi < i0)) {
                s0 = fminf(b0, os);
                b0 = ob; i0 = oi;
            } else {
                s0 = fminf(s0, ob);
            }
        }
        best[i] = b0; sec[i] = s0; bidx[i] = i0;
    }

    // publish per-row indices; flag near-ties into the block-local list
    if (m == 0) {
        #pragma unroll
        for (int r = 0; r < 4; ++r) {
            const int lrow = w * 16 + quad * 4 + r;
            ridx[lrow] = bidx[r];
            if (sec[r] - best[r] < TAU) {
                int p = atomicAdd(&nflag, 1);   // LDS atomic
                flags[p] = lrow;
            }
        }
    }
    __syncthreads();   // flags/ridx visible; drains leftover wraparound GLLs

    // ---- block-local exact repair: 1 code/thread x 4 passes per row ----
    // X row address is wave-uniform -> scalar loads; E row per thread (L2).
    const int nf = nflag;
    for (int f = 0; f < nf; ++f) {
        const int lrow = flags[f];
        const int row  = __builtin_amdgcn_readfirstlane(row0 + lrow);
        const float* xr = X + (size_t)row * DIM;
        float bb = 3.4e38f; int bi = 0;
        #pragma unroll
        for (int p = 0; p < 4; ++p) {
            const int c = p * 256 + tid;
            const float* er = E + (size_t)c * DIM;
            float s = 0.f;
            #pragma unroll 4
            for (int j = 0; j < DIM; j += 4) {
                float4 ev = *(const float4*)(er + j);
                float4 xv = *(const float4*)(xr + j);
                s += xv.x * ev.x + xv.y * ev.y + xv.z * ev.z + xv.w * ev.w;
            }
            float d = enorm[c] - 2.0f * s;
            if (d < bb) { bb = d; bi = c; }   // p ascending -> lowest idx kept
        }
        // wave reduce then cross-wave merge (lexicographic (d, idx))
        #pragma unroll
        for (int msk = 1; msk < 64; msk <<= 1) {
            float ob = __shfl_xor(bb, msk);
            int   oi = __shfl_xor(bi, msk);
            if (ob < bb || (ob == bb && oi < bi)) { bb = ob; bi = oi; }
        }
        if (lane == 0) { wrb[w] = bb; wri[w] = bi; }
        __syncthreads();
        if (tid == 0) {
            float fb = wrb[0]; int fi = wri[0];
            #pragma unroll
            for (int k = 1; k < 4; ++k)
                if (wrb[k] < fb || (wrb[k] == fb && wri[k] < fi)) { fb = wrb[k]; fi = wri[k]; }
            ridx[lrow] = fi;
        }
        __syncthreads();
    }

    // ---- fused epilogue: wave w writes rows [wrow, wrow+16) ----
    #pragma unroll 4
    for (int j = 0; j < 16; ++j) {
        const int lrow = w * 16 + j;
        const int idx  = ridx[lrow];
        const int row  = row0 + lrow;
        const size_t xb = (size_t)row * DIM + lane * 4;
        float4 x = *(const float4*)(X + xb);
        float4 q = *(const float4*)(E + (size_t)idx * DIM + lane * 4);
        float4 dl = {q.x - x.x, q.y - x.y, q.z - x.z, q.w - x.w};
        float4 lo = {0.25f * dl.x * dl.x, 0.25f * dl.y * dl.y,
                     0.25f * dl.z * dl.z, 0.25f * dl.w * dl.w};
        float4 qs = {x.x + dl.x, x.y + dl.y, x.z + dl.z, x.w + dl.w};
        *(float4*)(loss + xb) = lo;
        *(float4*)(qst + xb)  = qs;
        const size_t ob = (size_t)row * CODES;
        const int slot = idx >> 2, r3 = idx & 3;
        #pragma unroll
        for (int jj = 0; jj < 4; ++jj) {
            f32x4 z = {0.f, 0.f, 0.f, 0.f};
            if (slot == jj * 64 + lane) z[r3] = 1.0f;
            __builtin_nontemporal_store(z, (f32x4*)(onehot + ob + jj * 256 + lane * 4));
        }
    }
    #undef STAGE
}

extern "C" void kernel_launch(void* const* d_in, const int* in_sizes, int n_in,
                              void* d_out, int out_size, void* d_ws, size_t ws_size,
                              hipStream_t stream) {
    const float* X = (const float*)d_in[0];   // (65536, 256)
    const float* E = (const float*)d_in[1];   // (1024, 256)
    float* out = (float*)d_out;
    float* loss   = out;
    float* qst    = out + (size_t)BATCH * DIM;
    float* onehot = out + (size_t)2 * BATCH * DIM;

    char* ws = (char*)d_ws;
    float*          enorm  = (float*)ws;                        // 4 KB
    unsigned short* Eh     = (unsigned short*)(ws + 4096);      // 512 KB

    vq_prep<<<CODES, 64, 0, stream>>>(E, enorm, Eh);
    vq_fused<<<BATCH / 64, 256, 0, stream>>>(X, Eh, enorm, E,
                                             loss, qst, onehot);
}